// Round 1
// baseline (4438.185 us; speedup 1.0000x reference)
//
#include <hip/hip_runtime.h>
#include <hip/hip_cooperative_groups.h>

namespace cg = cooperative_groups;

// Problem constants: B=256, T=512, I=256, H=1024, O=128
constexpr int kB = 256;
constexpr int kT = 512;
constexpr int kI = 256;
constexpr int kH = 1024;
constexpr int kO = 128;

constexpr int kG   = 128;            // workgroups in cooperative kernel
constexpr int kNH  = kH / kG;        // 8 h-elements owned per WG
constexpr int kTPD = 256 / (2*kNH);  // 16 threads per dot
constexpr int kCHK = kH / kTPD;      // 64 h-elements per thread-chunk

// ---------------------------------------------------------------------------
// XP[b, j] = Bih[j] + dot(inputs[b, 511, :], Wih[j, :])   for j in [0, 2048)
// Only row t=511 of each batch element matters (scan emits h_new[-1] and rows
// of h evolve independently).
// ---------------------------------------------------------------------------
__global__ void xp_kernel(const float* __restrict__ inputs,
                          const float* __restrict__ Wih,
                          const float* __restrict__ Bih,
                          float* __restrict__ XP) {
    __shared__ __align__(16) float xs[kI];
    const int b = blockIdx.x;
    const int tid = threadIdx.x;
    xs[tid] = inputs[(size_t)b * (kT * kI) + (size_t)(kT - 1) * kI + tid];
    __syncthreads();
    #pragma unroll
    for (int r = 0; r < 8; ++r) {
        const int j = r * 256 + tid;
        const float4* wr = reinterpret_cast<const float4*>(Wih + (size_t)j * kI);
        const float4* xv = reinterpret_cast<const float4*>(xs);
        float acc = Bih[j];
        #pragma unroll
        for (int i = 0; i < kI / 4; ++i) {
            const float4 w = wr[i];
            const float4 x = xv[i];
            acc += w.x * x.x + w.y * x.y + w.z * x.z + w.w * x.w;
        }
        XP[b * (2 * kH) + j] = acc;
    }
}

// ---------------------------------------------------------------------------
// Persistent cooperative recurrence over b = 0..255.
//   hp = hvec @ Whh^T + Bhh  (2048 dots of length 1024)
//   fG = sigmoid(xf + hf); hG = tanh(xh + fG*hh)
//   h_new = (1-fG)*h + fG*hG;  lasts[b] = h_new
// Each WG owns kNH h-elements (2*kNH rows of Whh, held in registers:
// 64 fp32/thread). hvec double-buffered in global; one grid.sync per step.
// ---------------------------------------------------------------------------
__global__ void __launch_bounds__(256, 1)
recur_kernel(const float* __restrict__ Whh,
             const float* __restrict__ Bhh,
             const float* __restrict__ XP,
             float* __restrict__ hbuf,    // 2 * kH floats, buf0 zeroed
             float* __restrict__ lasts) { // kB * kH floats
    const int tid = threadIdx.x;
    const int wg  = blockIdx.x;
    const int hdbase = wg * kNH;
    const int d = tid >> 4;   // 0..15: which dot (0..7 = f-half, 8..15 = h-half)
    const int l = tid & 15;   // 0..15: lane within dot
    const int row = (d < kNH) ? (hdbase + d) : (kH + hdbase + (d - kNH));

    // Weights resident in VGPRs for the whole recurrence: 16 x float4 = 64 fp32
    float4 wv[16];
    {
        const float4* wr = reinterpret_cast<const float4*>(
            Whh + (size_t)row * kH + l * kCHK);
        #pragma unroll
        for (int i = 0; i < 16; ++i) wv[i] = wr[i];
    }

    // Padded LDS: index i -> i + 4*(i/64); chunk stride 68 floats = 272 B
    // (16B-aligned for ds_read_b128, 2-way bank aliasing only).
    __shared__ __align__(16) float sh[kH + 64];
    __shared__ float dres[2 * kNH];

    float bf = 0.f, bh = 0.f;
    if (tid < kNH) {
        bf = Bhh[hdbase + tid];
        bh = Bhh[kH + hdbase + tid];
    }

    cg::grid_group grid = cg::this_grid();

    for (int b = 0; b < kB; ++b) {
        const float* hsrc = hbuf + (b & 1) * kH;
        float* hdst       = hbuf + ((b + 1) & 1) * kH;

        __syncthreads();  // protect sh/dres reuse across iterations
        #pragma unroll
        for (int r = 0; r < 4; ++r) {
            const int i = tid + r * 256;
            sh[i + ((i >> 6) << 2)] = hsrc[i];
        }
        __syncthreads();

        // Partial dot over this thread's 64-element chunk
        const float4* shv = reinterpret_cast<const float4*>(sh + l * (kCHK + 4));
        float p = 0.f;
        #pragma unroll
        for (int i = 0; i < 16; ++i) {
            const float4 h4 = shv[i];
            p += wv[i].x * h4.x + wv[i].y * h4.y + wv[i].z * h4.z + wv[i].w * h4.w;
        }
        // Reduce across the 16 lanes of this dot group
        p += __shfl_xor(p, 8, 16);
        p += __shfl_xor(p, 4, 16);
        p += __shfl_xor(p, 2, 16);
        p += __shfl_xor(p, 1, 16);
        if (l == 0) dres[d] = p;
        __syncthreads();

        if (tid < kNH) {
            const int hd = hdbase + tid;
            const float xf = XP[b * (2 * kH) + hd];
            const float xh = XP[b * (2 * kH) + kH + hd];
            const float hf = dres[tid] + bf;
            const float hh = dres[kNH + tid] + bh;
            const float fG = 1.0f / (1.0f + expf(-(xf + hf)));
            const float hG = tanhf(xh + fG * hh);
            const float hprev = sh[hd + ((hd >> 6) << 2)];
            const float hnew = (1.0f - fG) * hprev + fG * hG;
            hdst[hd] = hnew;
            lasts[(size_t)b * kH + hd] = hnew;
        }
        grid.sync();  // h_new fully published before anyone starts step b+1
    }
}

// ---------------------------------------------------------------------------
// out[b, o] = Bout[o] + dot(lasts[b, :], Wout[o, :])
// ---------------------------------------------------------------------------
__global__ void out_kernel(const float* __restrict__ lasts,
                           const float* __restrict__ Wout,
                           const float* __restrict__ Bout,
                           float* __restrict__ out) {
    __shared__ __align__(16) float ls[kH];
    const int b = blockIdx.x;
    const int o = threadIdx.x;  // 128 threads
    #pragma unroll
    for (int r = 0; r < kH / 128; ++r)
        ls[o + r * 128] = lasts[(size_t)b * kH + o + r * 128];
    __syncthreads();
    const float4* wr = reinterpret_cast<const float4*>(Wout + (size_t)o * kH);
    const float4* lv = reinterpret_cast<const float4*>(ls);
    float acc = Bout[o];
    #pragma unroll 8
    for (int i = 0; i < kH / 4; ++i) {
        const float4 w = wr[i];
        const float4 x = lv[i];
        acc += w.x * x.x + w.y * x.y + w.z * x.z + w.w * x.w;
    }
    out[b * kO + o] = acc;
}

extern "C" void kernel_launch(void* const* d_in, const int* in_sizes, int n_in,
                              void* d_out, int out_size, void* d_ws, size_t ws_size,
                              hipStream_t stream) {
    const float* inputs = (const float*)d_in[0];
    const float* Wih    = (const float*)d_in[1];
    const float* Whh    = (const float*)d_in[2];
    const float* Bih    = (const float*)d_in[3];
    const float* Bhh    = (const float*)d_in[4];
    const float* Wout   = (const float*)d_in[5];
    const float* Bout   = (const float*)d_in[6];
    float* out = (float*)d_out;

    char* ws = (char*)d_ws;
    float* XP    = (float*)(ws);                                   // 256*2048 f32 = 2 MiB
    float* lasts = (float*)(ws + (size_t)kB * 2 * kH * 4);         // 256*1024 f32 = 1 MiB
    float* hbuf  = (float*)(ws + (size_t)kB * 2 * kH * 4
                               + (size_t)kB * kH * 4);             // 2*1024 f32

    // h0 = 0 (ws is poisoned 0xAA before every launch)
    hipMemsetAsync(hbuf, 0, 2 * kH * sizeof(float), stream);

    xp_kernel<<<dim3(kB), dim3(256), 0, stream>>>(inputs, Wih, Bih, XP);

    void* args[] = { (void*)&Whh, (void*)&Bhh, (void*)&XP,
                     (void*)&hbuf, (void*)&lasts };
    hipLaunchCooperativeKernel((void*)recur_kernel, dim3(kG), dim3(256),
                               args, 0, stream);

    out_kernel<<<dim3(kB), dim3(128), 0, stream>>>(lasts, Wout, Bout, out);
}

// Round 2
// 3056.981 us; speedup vs baseline: 1.4518x; 1.4518x over previous
//
#include <hip/hip_runtime.h>
#include <hip/hip_cooperative_groups.h>

// Problem constants: B=256, T=512, I=256, H=1024, O=128
constexpr int kB = 256;
constexpr int kT = 512;
constexpr int kI = 256;
constexpr int kH = 1024;
constexpr int kO = 128;

constexpr int kG   = 128;            // workgroups in cooperative kernel
constexpr int kNH  = kH / kG;        // 8 h-elements owned per WG
constexpr int kTPD = 16;             // threads per dot
constexpr int kCHK = kH / kTPD;      // 64 h-elements per thread-chunk
constexpr int kBB  = 8;              // batches per block in pre/post kernels

__device__ __forceinline__ void fence_rel_agent() {
    __builtin_amdgcn_fence(__ATOMIC_RELEASE, "agent");
}
__device__ __forceinline__ void fence_acq_agent() {
    __builtin_amdgcn_fence(__ATOMIC_ACQUIRE, "agent");
}

// ---------------------------------------------------------------------------
// XP[b, j] = Bih[j] + dot(inputs[b, T-1, :], Wih[j, :])   for j in [0, 2H)
// Only row t=511 matters (scan emits h_new[-1]; rows of h evolve
// independently). 8 batches per block so Wih is read 32x not 256x.
// ---------------------------------------------------------------------------
__global__ void xp_kernel(const float* __restrict__ inputs,
                          const float* __restrict__ Wih,
                          const float* __restrict__ Bih,
                          float* __restrict__ XP) {
    __shared__ __align__(16) float xs[kBB][kI];
    const int b0  = blockIdx.x * kBB;   // grid = 32
    const int tid = threadIdx.x;        // 256
    #pragma unroll
    for (int bb = 0; bb < kBB; ++bb)
        xs[bb][tid] = inputs[(size_t)(b0 + bb) * (kT * kI)
                             + (size_t)(kT - 1) * kI + tid];
    __syncthreads();
    #pragma unroll
    for (int r = 0; r < 8; ++r) {
        const int j = r * 256 + tid;
        const float4* wrow = reinterpret_cast<const float4*>(Wih + (size_t)j * kI);
        const float bj = Bih[j];
        float acc[kBB];
        #pragma unroll
        for (int bb = 0; bb < kBB; ++bb) acc[bb] = bj;
        for (int i = 0; i < kI / 4; ++i) {
            const float4 w = wrow[i];
            #pragma unroll
            for (int bb = 0; bb < kBB; ++bb) {
                const float4 x = reinterpret_cast<const float4*>(xs[bb])[i];
                acc[bb] += w.x * x.x + w.y * x.y + w.z * x.z + w.w * x.w;
            }
        }
        #pragma unroll
        for (int bb = 0; bb < kBB; ++bb)
            XP[(b0 + bb) * (2 * kH) + j] = acc[bb];
    }
}

// ---------------------------------------------------------------------------
// Persistent cooperative recurrence over b = 0..255 with a hand-rolled
// flag/epoch barrier (one release fence + relaxed flag store per WG, 128
// parallel relaxed-atomic pollers, one acquire fence) instead of
// cg::grid.sync()'s contended two-phase protocol.
// ---------------------------------------------------------------------------
__global__ void __launch_bounds__(256, 1)
recur_kernel(const float* __restrict__ Whh,
             const float* __restrict__ Bhh,
             const float* __restrict__ XP,
             float* __restrict__ hbuf,      // 2 * kH floats, buf0 zeroed
             float* __restrict__ lasts,     // kB * kH floats
             unsigned int* __restrict__ flags) {  // kG words, zeroed
    const int tid = threadIdx.x;
    const int wg  = blockIdx.x;
    const int hdbase = wg * kNH;
    const int d = tid >> 4;   // 0..15: which dot (0..7 = f-half, 8..15 = h-half)
    const int l = tid & 15;   // lane within dot
    const int row = (d < kNH) ? (hdbase + d) : (kH + hdbase + (d - kNH));

    // Weights resident in VGPRs for the whole recurrence: 16 x float4 = 64 fp32
    float4 wv[16];
    {
        const float4* wr = reinterpret_cast<const float4*>(
            Whh + (size_t)row * kH + l * kCHK);
        #pragma unroll
        for (int i = 0; i < 16; ++i) wv[i] = wr[i];
    }

    // Padded LDS: index i -> i + 4*(i/64); chunk stride 68 floats = 272 B.
    __shared__ __align__(16) float sh[kH + 64];
    __shared__ float dres[2 * kNH];

    float bf = 0.f, bh = 0.f;
    if (tid < kNH) {
        bf = Bhh[hdbase + tid];
        bh = Bhh[kH + hdbase + tid];
    }

    for (int b = 0; b < kB; ++b) {
        const float* hsrc = hbuf + (b & 1) * kH;
        float* hdst       = hbuf + ((b + 1) & 1) * kH;

        #pragma unroll
        for (int r = 0; r < 4; ++r) {
            const int i = tid + r * 256;
            sh[i + ((i >> 6) << 2)] = hsrc[i];
        }
        __syncthreads();

        // Partial dot over this thread's 64-element chunk
        const float4* shv = reinterpret_cast<const float4*>(sh + l * (kCHK + 4));
        float p = 0.f;
        #pragma unroll
        for (int i = 0; i < 16; ++i) {
            const float4 h4 = shv[i];
            p += wv[i].x * h4.x + wv[i].y * h4.y + wv[i].z * h4.z + wv[i].w * h4.w;
        }
        p += __shfl_xor(p, 8, 16);
        p += __shfl_xor(p, 4, 16);
        p += __shfl_xor(p, 2, 16);
        p += __shfl_xor(p, 1, 16);
        if (l == 0) dres[d] = p;
        __syncthreads();

        if (tid < kNH) {
            const int hd = hdbase + tid;
            const float xf = XP[b * (2 * kH) + hd];
            const float xh = XP[b * (2 * kH) + kH + hd];
            const float hf = dres[tid] + bf;
            const float hh = dres[kNH + tid] + bh;
            const float fG = 1.0f / (1.0f + expf(-(xf + hf)));
            const float hG = tanhf(xh + fG * hh);
            const float hprev = sh[hd + ((hd >> 6) << 2)];
            const float hnew = (1.0f - fG) * hprev + fG * hG;
            hdst[hd] = hnew;
            lasts[(size_t)b * kH + hd] = hnew;
        }

        // --- publish + barrier ---
        // h stores were done by tid<8 (wave 0); flag store by tid 0 is in the
        // same wave, so program order + one release fence suffices.
        if ((tid >> 6) == 0) {
            fence_rel_agent();
            if (tid == 0)
                __hip_atomic_store(&flags[wg], (unsigned)(b + 1),
                                   __ATOMIC_RELAXED, __HIP_MEMORY_SCOPE_AGENT);
        }
        // Thread i polls WG i's flag; relaxed agent loads read the coherence
        // point, so no per-poll cache invalidate.
        if (tid < kG) {
            while (__hip_atomic_load(&flags[tid], __ATOMIC_RELAXED,
                                     __HIP_MEMORY_SCOPE_AGENT) < (unsigned)(b + 1)) {}
        }
        __syncthreads();
        fence_acq_agent();  // one L1/L2 invalidate; next hsrc read sees fresh h
    }
}

// ---------------------------------------------------------------------------
// out[b, o] = Bout[o] + dot(lasts[b, :], Wout[o, :]); 8 batches per block.
// ---------------------------------------------------------------------------
__global__ void out_kernel(const float* __restrict__ lasts,
                           const float* __restrict__ Wout,
                           const float* __restrict__ Bout,
                           float* __restrict__ out) {
    __shared__ __align__(16) float ls[kBB][kH];  // 32 KiB
    const int b0  = blockIdx.x * kBB;   // grid = 32
    const int tid = threadIdx.x;        // 128
    #pragma unroll
    for (int bb = 0; bb < kBB; ++bb)
        for (int r = 0; r < kH / 128; ++r)
            ls[bb][tid + r * 128] = lasts[(size_t)(b0 + bb) * kH + tid + r * 128];
    __syncthreads();
    const float4* wrow = reinterpret_cast<const float4*>(Wout + (size_t)tid * kH);
    const float bo = Bout[tid];
    float acc[kBB];
    #pragma unroll
    for (int bb = 0; bb < kBB; ++bb) acc[bb] = bo;
    for (int i = 0; i < kH / 4; ++i) {
        const float4 w = wrow[i];
        #pragma unroll
        for (int bb = 0; bb < kBB; ++bb) {
            const float4 x = reinterpret_cast<const float4*>(ls[bb])[i];
            acc[bb] += w.x * x.x + w.y * x.y + w.z * x.z + w.w * x.w;
        }
    }
    #pragma unroll
    for (int bb = 0; bb < kBB; ++bb)
        out[(b0 + bb) * kO + tid] = acc[bb];
}

extern "C" void kernel_launch(void* const* d_in, const int* in_sizes, int n_in,
                              void* d_out, int out_size, void* d_ws, size_t ws_size,
                              hipStream_t stream) {
    const float* inputs = (const float*)d_in[0];
    const float* Wih    = (const float*)d_in[1];
    const float* Whh    = (const float*)d_in[2];
    const float* Bih    = (const float*)d_in[3];
    const float* Bhh    = (const float*)d_in[4];
    const float* Wout   = (const float*)d_in[5];
    const float* Bout   = (const float*)d_in[6];
    float* out = (float*)d_out;

    char* ws = (char*)d_ws;
    float* XP    = (float*)(ws);                                   // 256*2048 f32 = 2 MiB
    float* lasts = (float*)(ws + (size_t)kB * 2 * kH * 4);         // 256*1024 f32 = 1 MiB
    float* hbuf  = (float*)(ws + (size_t)kB * 2 * kH * 4
                               + (size_t)kB * kH * 4);             // 2*1024 f32
    unsigned int* flags = (unsigned int*)(ws + (size_t)kB * 2 * kH * 4
                                             + (size_t)kB * kH * 4
                                             + (size_t)2 * kH * 4); // kG words

    // h0 = 0 and flags = 0 (ws is poisoned 0xAA before every launch)
    hipMemsetAsync(hbuf, 0, 2 * kH * sizeof(float) + kG * sizeof(unsigned int),
                   stream);

    xp_kernel<<<dim3(kB / kBB), dim3(256), 0, stream>>>(inputs, Wih, Bih, XP);

    void* args[] = { (void*)&Whh, (void*)&Bhh, (void*)&XP,
                     (void*)&hbuf, (void*)&lasts, (void*)&flags };
    hipLaunchCooperativeKernel((void*)recur_kernel, dim3(kG), dim3(256),
                               args, 0, stream);

    out_kernel<<<dim3(kB / kBB), dim3(128), 0, stream>>>(lasts, Wout, Bout, out);
}

// Round 3
// 1655.624 us; speedup vs baseline: 2.6807x; 1.8464x over previous
//
#include <hip/hip_runtime.h>
#include <hip/hip_cooperative_groups.h>

// Problem constants: B=256, T=512, I=256, H=1024, O=128
constexpr int kB = 256;
constexpr int kT = 512;
constexpr int kI = 256;
constexpr int kH = 1024;
constexpr int kO = 128;

constexpr int kG   = 128;            // workgroups in cooperative kernel
constexpr int kNH  = kH / kG;        // 8 h-elements owned per WG
constexpr int kTPD = 16;             // threads per dot
constexpr int kCHK = kH / kTPD;      // 64 h-elements per thread-chunk
constexpr int kBB  = 8;              // batches per block in pre/post kernels

typedef float f32x4 __attribute__((ext_vector_type(4)));

// ---------------------------------------------------------------------------
// XP[b, j] = Bih[j] + dot(inputs[b, T-1, :], Wih[j, :])   for j in [0, 2H)
// Only row t=511 matters (scan emits h_new[-1]; rows of h evolve
// independently). 8 batches per block so Wih is read 32x not 256x.
// ---------------------------------------------------------------------------
__global__ void xp_kernel(const float* __restrict__ inputs,
                          const float* __restrict__ Wih,
                          const float* __restrict__ Bih,
                          float* __restrict__ XP) {
    __shared__ __align__(16) float xs[kBB][kI];
    const int b0  = blockIdx.x * kBB;   // grid = 32
    const int tid = threadIdx.x;        // 256
    #pragma unroll
    for (int bb = 0; bb < kBB; ++bb)
        xs[bb][tid] = inputs[(size_t)(b0 + bb) * (kT * kI)
                             + (size_t)(kT - 1) * kI + tid];
    __syncthreads();
    #pragma unroll
    for (int r = 0; r < 8; ++r) {
        const int j = r * 256 + tid;
        const float4* wrow = reinterpret_cast<const float4*>(Wih + (size_t)j * kI);
        const float bj = Bih[j];
        float acc[kBB];
        #pragma unroll
        for (int bb = 0; bb < kBB; ++bb) acc[bb] = bj;
        for (int i = 0; i < kI / 4; ++i) {
            const float4 w = wrow[i];
            #pragma unroll
            for (int bb = 0; bb < kBB; ++bb) {
                const float4 x = reinterpret_cast<const float4*>(xs[bb])[i];
                acc[bb] += w.x * x.x + w.y * x.y + w.z * x.z + w.w * x.w;
            }
        }
        #pragma unroll
        for (int bb = 0; bb < kBB; ++bb)
            XP[(b0 + bb) * (2 * kH) + j] = acc[bb];
    }
}

// ---------------------------------------------------------------------------
// Persistent cooperative recurrence over b = 0..255.
// All cross-WG traffic (h vector, flags) uses sc0/sc1 cache-bypass accesses
// (coherence point = Infinity Cache), so NO cache-maintenance fences are
// needed: release = s_waitcnt vmcnt(0) in the producing wave before the flag
// store; acquire = in-order issue after the poll (bypass loads can't read a
// stale cache). L2 stays warm for XP across all 256 steps.
// Whh weights are pinned in VGPRs via opaque inline-asm loads (the compiler
// cannot rematerialize asm outputs, unlike loop-invariant const loads).
// ---------------------------------------------------------------------------
__global__ void __launch_bounds__(256, 1)
recur_kernel(const float* __restrict__ Whh,
             const float* __restrict__ Bhh,
             const float* __restrict__ XP,
             float* __restrict__ hbuf,      // 2 * kH floats, zeroed
             float* __restrict__ lasts,     // kB * kH floats
             unsigned int* __restrict__ flags) {  // kG words, zeroed
    const int tid = threadIdx.x;
    const int wg  = blockIdx.x;
    const int hdbase = wg * kNH;
    const int d = tid >> 4;   // 0..15: which dot (0..7 = f-half, 8..15 = h-half)
    const int l = tid & 15;   // lane within dot
    const int row = (d < kNH) ? (hdbase + d) : (kH + hdbase + (d - kNH));

    // Weights resident in VGPRs for the whole recurrence: 16 x f32x4 = 64 fp32.
    f32x4 wv[16];
    {
        const float* wbase = Whh + (size_t)row * kH + l * kCHK;
        asm volatile(
            "global_load_dwordx4 %0, %16, off\n\t"
            "global_load_dwordx4 %1, %16, off offset:16\n\t"
            "global_load_dwordx4 %2, %16, off offset:32\n\t"
            "global_load_dwordx4 %3, %16, off offset:48\n\t"
            "global_load_dwordx4 %4, %16, off offset:64\n\t"
            "global_load_dwordx4 %5, %16, off offset:80\n\t"
            "global_load_dwordx4 %6, %16, off offset:96\n\t"
            "global_load_dwordx4 %7, %16, off offset:112\n\t"
            "global_load_dwordx4 %8, %16, off offset:128\n\t"
            "global_load_dwordx4 %9, %16, off offset:144\n\t"
            "global_load_dwordx4 %10, %16, off offset:160\n\t"
            "global_load_dwordx4 %11, %16, off offset:176\n\t"
            "global_load_dwordx4 %12, %16, off offset:192\n\t"
            "global_load_dwordx4 %13, %16, off offset:208\n\t"
            "global_load_dwordx4 %14, %16, off offset:224\n\t"
            "global_load_dwordx4 %15, %16, off offset:240\n\t"
            "s_waitcnt vmcnt(0)"
            : "=&v"(wv[0]), "=&v"(wv[1]), "=&v"(wv[2]), "=&v"(wv[3]),
              "=&v"(wv[4]), "=&v"(wv[5]), "=&v"(wv[6]), "=&v"(wv[7]),
              "=&v"(wv[8]), "=&v"(wv[9]), "=&v"(wv[10]), "=&v"(wv[11]),
              "=&v"(wv[12]), "=&v"(wv[13]), "=&v"(wv[14]), "=&v"(wv[15])
            : "v"(wbase));
    }

    // Padded LDS: index i -> i + 4*(i/64); chunk stride 68 floats = 272 B
    // (16B-aligned so f32x4 stores/loads stay ds_*_b128; 2-way bank aliasing
    // only, which is free on CDNA4).
    __shared__ __align__(16) float sh[kH + 64];
    __shared__ float dres[2 * kNH];

    float bf = 0.f, bh = 0.f;
    if (tid < kNH) {
        bf = Bhh[hdbase + tid];
        bh = Bhh[kH + hdbase + tid];
    }

    for (int b = 0; b < kB; ++b) {
        const float* hsrc = hbuf + (b & 1) * kH;
        float* hdst       = hbuf + ((b + 1) & 1) * kH;

        // Stage h through LDS: one 16B coherence-point load per thread.
        {
            f32x4 h4;
            const float* hap = hsrc + tid * 4;
            asm volatile(
                "global_load_dwordx4 %0, %1, off sc0 sc1\n\t"
                "s_waitcnt vmcnt(0)"
                : "=v"(h4) : "v"(hap) : "memory");
            const int i0 = tid * 4;
            *reinterpret_cast<f32x4*>(&sh[i0 + ((i0 >> 6) << 2)]) = h4;
        }
        __syncthreads();

        // Partial dot over this thread's 64-element chunk.
        const f32x4* shv = reinterpret_cast<const f32x4*>(sh + l * (kCHK + 4));
        float p = 0.f;
        #pragma unroll
        for (int i = 0; i < 16; ++i) {
            const f32x4 h4 = shv[i];
            p += wv[i].x * h4.x + wv[i].y * h4.y + wv[i].z * h4.z + wv[i].w * h4.w;
        }
        p += __shfl_xor(p, 8, 16);
        p += __shfl_xor(p, 4, 16);
        p += __shfl_xor(p, 2, 16);
        p += __shfl_xor(p, 1, 16);
        if (l == 0) dres[d] = p;
        __syncthreads();

        if (tid < kNH) {
            const int hd = hdbase + tid;
            const float xf = XP[b * (2 * kH) + hd];          // L2-warm
            const float xh = XP[b * (2 * kH) + kH + hd];
            const float hf = dres[tid] + bf;
            const float hh = dres[kNH + tid] + bh;
            const float fG = 1.0f / (1.0f + expf(-(xf + hf)));
            const float hG = tanhf(xh + fG * hh);
            const float hprev = sh[hd + ((hd >> 6) << 2)];
            const float hnew = (1.0f - fG) * hprev + fG * hG;
            // Publish h at the coherence point (bypass L1/L2).
            asm volatile("global_store_dword %0, %1, off sc0 sc1"
                         :: "v"(&hdst[hd]), "v"(hnew) : "memory");
            lasts[(size_t)b * kH + hd] = hnew;               // cached; read later
        }

        // --- release: h stores (wave 0) ack'd at coherence point, then flag.
        if ((tid >> 6) == 0) {
            asm volatile("s_waitcnt vmcnt(0)" ::: "memory");
            if (tid == 0) {
                const unsigned int fv = (unsigned)(b + 1);
                asm volatile("global_store_dword %0, %1, off sc0 sc1"
                             :: "v"(&flags[wg]), "v"(fv) : "memory");
            }
        }
        // --- barrier: thread i polls WG i's flag at the coherence point.
        if (tid < kG) {
            while (__hip_atomic_load(&flags[tid], __ATOMIC_RELAXED,
                                     __HIP_MEMORY_SCOPE_AGENT) < (unsigned)(b + 1)) {}
        }
        __syncthreads();
        // No acquire fence needed: next h loads bypass L1/L2 and are issued
        // in-order after the poll.
    }
}

// ---------------------------------------------------------------------------
// out[b, o] = Bout[o] + dot(lasts[b, :], Wout[o, :]); 8 batches per block.
// ---------------------------------------------------------------------------
__global__ void out_kernel(const float* __restrict__ lasts,
                           const float* __restrict__ Wout,
                           const float* __restrict__ Bout,
                           float* __restrict__ out) {
    __shared__ __align__(16) float ls[kBB][kH];  // 32 KiB
    const int b0  = blockIdx.x * kBB;   // grid = 32
    const int tid = threadIdx.x;        // 128
    #pragma unroll
    for (int bb = 0; bb < kBB; ++bb)
        for (int r = 0; r < kH / 128; ++r)
            ls[bb][tid + r * 128] = lasts[(size_t)(b0 + bb) * kH + tid + r * 128];
    __syncthreads();
    const float4* wrow = reinterpret_cast<const float4*>(Wout + (size_t)tid * kH);
    const float bo = Bout[tid];
    float acc[kBB];
    #pragma unroll
    for (int bb = 0; bb < kBB; ++bb) acc[bb] = bo;
    for (int i = 0; i < kH / 4; ++i) {
        const float4 w = wrow[i];
        #pragma unroll
        for (int bb = 0; bb < kBB; ++bb) {
            const float4 x = reinterpret_cast<const float4*>(ls[bb])[i];
            acc[bb] += w.x * x.x + w.y * x.y + w.z * x.z + w.w * x.w;
        }
    }
    #pragma unroll
    for (int bb = 0; bb < kBB; ++bb)
        out[(b0 + bb) * kO + tid] = acc[bb];
}

extern "C" void kernel_launch(void* const* d_in, const int* in_sizes, int n_in,
                              void* d_out, int out_size, void* d_ws, size_t ws_size,
                              hipStream_t stream) {
    const float* inputs = (const float*)d_in[0];
    const float* Wih    = (const float*)d_in[1];
    const float* Whh    = (const float*)d_in[2];
    const float* Bih    = (const float*)d_in[3];
    const float* Bhh    = (const float*)d_in[4];
    const float* Wout   = (const float*)d_in[5];
    const float* Bout   = (const float*)d_in[6];
    float* out = (float*)d_out;

    char* ws = (char*)d_ws;
    float* XP    = (float*)(ws);                                   // 256*2048 f32 = 2 MiB
    float* lasts = (float*)(ws + (size_t)kB * 2 * kH * 4);         // 256*1024 f32 = 1 MiB
    float* hbuf  = (float*)(ws + (size_t)kB * 2 * kH * 4
                               + (size_t)kB * kH * 4);             // 2*1024 f32
    unsigned int* flags = (unsigned int*)(ws + (size_t)kB * 2 * kH * 4
                                             + (size_t)kB * kH * 4
                                             + (size_t)2 * kH * 4); // kG words

    // h0 = 0 and flags = 0 (ws is poisoned 0xAA before every launch)
    hipMemsetAsync(hbuf, 0, 2 * kH * sizeof(float) + kG * sizeof(unsigned int),
                   stream);

    xp_kernel<<<dim3(kB / kBB), dim3(256), 0, stream>>>(inputs, Wih, Bih, XP);

    void* args[] = { (void*)&Whh, (void*)&Bhh, (void*)&XP,
                     (void*)&hbuf, (void*)&lasts, (void*)&flags };
    hipLaunchCooperativeKernel((void*)recur_kernel, dim3(kG), dim3(256),
                               args, 0, stream);

    out_kernel<<<dim3(kB / kBB), dim3(128), 0, stream>>>(lasts, Wout, Bout, out);
}

// Round 5
// 886.189 us; speedup vs baseline: 5.0082x; 1.8683x over previous
//
#include <hip/hip_runtime.h>
#include <hip/hip_cooperative_groups.h>

// Problem constants: B=256, T=512, I=256, H=1024, O=128
constexpr int kB = 256;
constexpr int kT = 512;
constexpr int kI = 256;
constexpr int kH = 1024;
constexpr int kO = 128;

constexpr int kG   = 128;            // workgroups in cooperative kernel
constexpr int kNH  = kH / kG;        // 8 h-elements owned per WG
constexpr int kTPD = 16;             // threads per dot
constexpr int kCHK = kH / kTPD;      // 64 h-elements per thread-chunk
constexpr int kBB  = 8;              // batches per block in pre/post kernels

typedef float f32x4 __attribute__((ext_vector_type(4)));
typedef unsigned int u32x2 __attribute__((ext_vector_type(2)));
typedef unsigned int u32x4 __attribute__((ext_vector_type(4)));

// ---------------------------------------------------------------------------
// XP[b, j] = Bih[j] + dot(inputs[b, T-1, :], Wih[j, :])   for j in [0, 2H)
// Only row t=511 matters (scan emits h_new[-1]; rows of h evolve
// independently). 8 batches per block so Wih is read 32x not 256x.
// ---------------------------------------------------------------------------
__global__ void xp_kernel(const float* __restrict__ inputs,
                          const float* __restrict__ Wih,
                          const float* __restrict__ Bih,
                          float* __restrict__ XP) {
    __shared__ __align__(16) float xs[kBB][kI];
    const int b0  = blockIdx.x * kBB;   // grid = 32
    const int tid = threadIdx.x;        // 256
    #pragma unroll
    for (int bb = 0; bb < kBB; ++bb)
        xs[bb][tid] = inputs[(size_t)(b0 + bb) * (kT * kI)
                             + (size_t)(kT - 1) * kI + tid];
    __syncthreads();
    #pragma unroll
    for (int r = 0; r < 8; ++r) {
        const int j = r * 256 + tid;
        const float4* wrow = reinterpret_cast<const float4*>(Wih + (size_t)j * kI);
        const float bj = Bih[j];
        float acc[kBB];
        #pragma unroll
        for (int bb = 0; bb < kBB; ++bb) acc[bb] = bj;
        for (int i = 0; i < kI / 4; ++i) {
            const float4 w = wrow[i];
            #pragma unroll
            for (int bb = 0; bb < kBB; ++bb) {
                const float4 x = reinterpret_cast<const float4*>(xs[bb])[i];
                acc[bb] += w.x * x.x + w.y * x.y + w.z * x.z + w.w * x.w;
            }
        }
        #pragma unroll
        for (int bb = 0; bb < kBB; ++bb)
            XP[(b0 + bb) * (2 * kH) + j] = acc[bb];
    }
}

// ---------------------------------------------------------------------------
// Persistent recurrence over b = 0..255, synchronized purely by DATAFLOW:
// each h entry is an 8B {f32 value, u32 epoch} word at the coherence point
// (sc0 sc1 bypasses the non-coherent L1/L2). Consumers poll their entries
// until epoch == step; the poll load IS the data load. Two-buffer parity +
// the all-to-all dependency bound WG skew to <=1 step, so no grid barrier,
// no flags, no fences, no vmcnt acks are needed anywhere.
//
// Epoch protocol: step b reads hbuf[b&1] expecting tag b (buffer memset to
// 0 => step 0 reads h=0/tag 0), writes its 8 entries to hbuf[(b+1)&1] with
// tag b+1. A producer can only reach step s+2 (overwriting tags s+1) after
// every WG published s+2, i.e. after every WG finished READING tags s+1.
// ---------------------------------------------------------------------------
__global__ void __launch_bounds__(256, 1)
recur_kernel(const float* __restrict__ Whh,
             const float* __restrict__ Bhh,
             const float* __restrict__ XP,
             unsigned long long* __restrict__ hbuf,  // 2 * kH entries, zeroed
             float* __restrict__ lasts) {            // kB * kH floats
    const int tid = threadIdx.x;
    const int wg  = blockIdx.x;
    const int hdbase = wg * kNH;
    const int d = tid >> 4;   // 0..15: which dot (0..7 = f-half, 8..15 = h-half)
    const int l = tid & 15;   // lane within dot
    const int row = (d < kNH) ? (hdbase + d) : (kH + hdbase + (d - kNH));

    // Weights resident in registers for the whole recurrence: 16 x f32x4.
    // Opaque asm outputs cannot be rematerialized by the compiler.
    f32x4 wv[16];
    {
        const float* wbase = Whh + (size_t)row * kH + l * kCHK;
        asm volatile(
            "global_load_dwordx4 %0, %16, off\n\t"
            "global_load_dwordx4 %1, %16, off offset:16\n\t"
            "global_load_dwordx4 %2, %16, off offset:32\n\t"
            "global_load_dwordx4 %3, %16, off offset:48\n\t"
            "global_load_dwordx4 %4, %16, off offset:64\n\t"
            "global_load_dwordx4 %5, %16, off offset:80\n\t"
            "global_load_dwordx4 %6, %16, off offset:96\n\t"
            "global_load_dwordx4 %7, %16, off offset:112\n\t"
            "global_load_dwordx4 %8, %16, off offset:128\n\t"
            "global_load_dwordx4 %9, %16, off offset:144\n\t"
            "global_load_dwordx4 %10, %16, off offset:160\n\t"
            "global_load_dwordx4 %11, %16, off offset:176\n\t"
            "global_load_dwordx4 %12, %16, off offset:192\n\t"
            "global_load_dwordx4 %13, %16, off offset:208\n\t"
            "global_load_dwordx4 %14, %16, off offset:224\n\t"
            "global_load_dwordx4 %15, %16, off offset:240\n\t"
            "s_waitcnt vmcnt(0)"
            : "=&v"(wv[0]), "=&v"(wv[1]), "=&v"(wv[2]), "=&v"(wv[3]),
              "=&v"(wv[4]), "=&v"(wv[5]), "=&v"(wv[6]), "=&v"(wv[7]),
              "=&v"(wv[8]), "=&v"(wv[9]), "=&v"(wv[10]), "=&v"(wv[11]),
              "=&v"(wv[12]), "=&v"(wv[13]), "=&v"(wv[14]), "=&v"(wv[15])
            : "v"(wbase));
    }

    // Padded LDS: index i -> i + 4*(i/64); chunk stride 68 floats = 272 B
    // (16B-aligned; 2-way bank aliasing only, free on CDNA4).
    __shared__ __align__(16) float sh[kH + 64];
    __shared__ float dres[2 * kNH];

    float bf = 0.f, bh = 0.f;
    if (tid < kNH) {
        bf = Bhh[hdbase + tid];
        bh = Bhh[kH + hdbase + tid];
    }

    for (int b = 0; b < kB; ++b) {
        const unsigned long long* hsrc = hbuf + (size_t)(b & 1) * kH;
        unsigned long long* hdst       = hbuf + (size_t)((b + 1) & 1) * kH;

        // Prefetch XP (cached, L2-warm) so its latency hides under the poll.
        float xf = 0.f, xh = 0.f;
        if (tid < kNH) {
            xf = XP[b * (2 * kH) + hdbase + tid];
            xh = XP[b * (2 * kH) + kH + hdbase + tid];
        }

        // Poll this thread's 4 entries (32B) until all tags == b.
        u32x4 A, C;
        {
            const unsigned long long* pollp = hsrc + (size_t)tid * 4;
            const unsigned expt = (unsigned)b;
            do {
                asm volatile(
                    "global_load_dwordx4 %0, %2, off sc0 sc1\n\t"
                    "global_load_dwordx4 %1, %2, off offset:16 sc0 sc1\n\t"
                    "s_waitcnt vmcnt(0)"
                    : "=v"(A), "=v"(C) : "v"(pollp) : "memory");
            } while (A.y != expt || A.w != expt || C.y != expt || C.w != expt);
        }
        // Stage the 4 values into LDS (padded).
        {
            const int i0 = tid * 4;
            f32x4 hv;
            hv.x = __uint_as_float(A.x);
            hv.y = __uint_as_float(A.z);
            hv.z = __uint_as_float(C.x);
            hv.w = __uint_as_float(C.z);
            *reinterpret_cast<f32x4*>(&sh[i0 + ((i0 >> 6) << 2)]) = hv;
        }
        __syncthreads();

        // hprev read must complete before sync2 (next step's stagers rewrite sh).
        float hprev = 0.f;
        if (tid < kNH) {
            const int hd = hdbase + tid;
            hprev = sh[hd + ((hd >> 6) << 2)];
        }

        // Partial dot over this thread's 64-element chunk.
        const f32x4* shv = reinterpret_cast<const f32x4*>(sh + l * (kCHK + 4));
        float p = 0.f;
        #pragma unroll
        for (int i = 0; i < 16; ++i) {
            const f32x4 h4 = shv[i];
            p += wv[i].x * h4.x + wv[i].y * h4.y + wv[i].z * h4.z + wv[i].w * h4.w;
        }
        p += __shfl_xor(p, 8, 16);
        p += __shfl_xor(p, 4, 16);
        p += __shfl_xor(p, 2, 16);
        p += __shfl_xor(p, 1, 16);
        if (l == 0) dres[d] = p;
        __syncthreads();

        if (tid < kNH) {
            const int hd = hdbase + tid;
            const float hf = dres[tid] + bf;
            const float hh = dres[kNH + tid] + bh;
            const float z1 = xf + hf;
            const float fG = 1.0f / (1.0f + __expf(-z1));
            const float z2 = xh + fG * hh;
            const float az = fabsf(z2);
            const float e2 = __expf(2.0f * az);
            const float hG = copysignf(1.0f - 2.0f / (e2 + 1.0f), z2);
            const float hnew = (1.0f - fG) * hprev + fG * hG;
            // Publish {value, epoch} in ONE 8B store at the coherence point:
            // tag rides with the data, so no ack, no flag, no fence.
            u32x2 pk;
            pk.x = __float_as_uint(hnew);
            pk.y = (unsigned)(b + 1);
            asm volatile("global_store_dwordx2 %0, %1, off sc0 sc1"
                         :: "v"(hdst + hd), "v"(pk) : "memory");
            lasts[(size_t)b * kH + hd] = hnew;   // cached; read by out_kernel
        }
        // No barrier: next step's poll self-synchronizes on the tags.
    }
}

// ---------------------------------------------------------------------------
// out[b, o] = Bout[o] + dot(lasts[b, :], Wout[o, :]); 8 batches per block.
// ---------------------------------------------------------------------------
__global__ void out_kernel(const float* __restrict__ lasts,
                           const float* __restrict__ Wout,
                           const float* __restrict__ Bout,
                           float* __restrict__ out) {
    __shared__ __align__(16) float ls[kBB][kH];  // 32 KiB
    const int b0  = blockIdx.x * kBB;   // grid = 32
    const int tid = threadIdx.x;        // 128
    #pragma unroll
    for (int bb = 0; bb < kBB; ++bb)
        for (int r = 0; r < kH / 128; ++r)
            ls[bb][tid + r * 128] = lasts[(size_t)(b0 + bb) * kH + tid + r * 128];
    __syncthreads();
    const float4* wrow = reinterpret_cast<const float4*>(Wout + (size_t)tid * kH);
    const float bo = Bout[tid];
    float acc[kBB];
    #pragma unroll
    for (int bb = 0; bb < kBB; ++bb) acc[bb] = bo;
    for (int i = 0; i < kH / 4; ++i) {
        const float4 w = wrow[i];
        #pragma unroll
        for (int bb = 0; bb < kBB; ++bb) {
            const float4 x = reinterpret_cast<const float4*>(ls[bb])[i];
            acc[bb] += w.x * x.x + w.y * x.y + w.z * x.z + w.w * x.w;
        }
    }
    #pragma unroll
    for (int bb = 0; bb < kBB; ++bb)
        out[(b0 + bb) * kO + tid] = acc[bb];
}

extern "C" void kernel_launch(void* const* d_in, const int* in_sizes, int n_in,
                              void* d_out, int out_size, void* d_ws, size_t ws_size,
                              hipStream_t stream) {
    const float* inputs = (const float*)d_in[0];
    const float* Wih    = (const float*)d_in[1];
    const float* Whh    = (const float*)d_in[2];
    const float* Bih    = (const float*)d_in[3];
    const float* Bhh    = (const float*)d_in[4];
    const float* Wout   = (const float*)d_in[5];
    const float* Bout   = (const float*)d_in[6];
    float* out = (float*)d_out;

    char* ws = (char*)d_ws;
    float* XP    = (float*)(ws);                                   // 256*2048 f32 = 2 MiB
    float* lasts = (float*)(ws + (size_t)kB * 2 * kH * 4);         // 256*1024 f32 = 1 MiB
    unsigned long long* hbuf = (unsigned long long*)
        (ws + (size_t)kB * 2 * kH * 4 + (size_t)kB * kH * 4);      // 2*kH x 8B = 16 KiB

    // hbuf = {h=0, tag=0}: step 0 reads zeros with epoch 0.
    hipMemsetAsync(hbuf, 0, 2 * kH * sizeof(unsigned long long), stream);

    xp_kernel<<<dim3(kB / kBB), dim3(256), 0, stream>>>(inputs, Wih, Bih, XP);

    void* args[] = { (void*)&Whh, (void*)&Bhh, (void*)&XP,
                     (void*)&hbuf, (void*)&lasts };
    hipLaunchCooperativeKernel((void*)recur_kernel, dim3(kG), dim3(256),
                               args, 0, stream);

    out_kernel<<<dim3(kB / kBB), dim3(128), 0, stream>>>(lasts, Wout, Bout, out);
}